// Round 3
// baseline (547.503 us; speedup 1.0000x reference)
//
#include <hip/hip_runtime.h>
#include <hip/hip_fp16.h>

#define NUM_USERS 100000
#define NN        200000          // N = users + items
#define DD        64
#define EE        3200000
#define SCAN_CHUNK 2048
#define NB_SCAN   98              // covers up to 200704 elements

#define KB_   391                 // dst buckets: 512 nodes each (dst >> 9)
#define GSEG  512                 // edge segments
#define EPS   (EE / GSEG)         // 6250 edges per segment
#define MSEG  (KB_ * GSEG)        // 200192 (bucket,segment) counters

typedef _Float16 half8 __attribute__((ext_vector_type(8)));
typedef _Float16 half4 __attribute__((ext_vector_type(4)));
typedef float    f32x4 __attribute__((ext_vector_type(4)));

// ---------------------------------------------------------------------------
// Generic 3-phase exclusive scan (len <= NB_SCAN*SCAN_CHUNK).
// ---------------------------------------------------------------------------
__global__ __launch_bounds__(256) void scan_partials_kernel(
    const int* __restrict__ counts, int* __restrict__ bsum, int len)
{
    __shared__ int s[256];
    const int t = threadIdx.x;
    int sum = 0;
    for (int i = t; i < SCAN_CHUNK; i += 256) {
        const int idx = blockIdx.x * SCAN_CHUNK + i;
        sum += (idx < len) ? counts[idx] : 0;
    }
    s[t] = sum; __syncthreads();
    for (int off = 128; off > 0; off >>= 1) {
        if (t < off) s[t] += s[t + off];
        __syncthreads();
    }
    if (t == 0) bsum[blockIdx.x] = s[0];
}

__global__ __launch_bounds__(128) void scan_top_kernel(int* __restrict__ bsum, int nb)
{
    __shared__ int s[128];
    const int t = threadIdx.x;
    const int v = (t < nb) ? bsum[t] : 0;
    s[t] = v; __syncthreads();
    for (int off = 1; off < 128; off <<= 1) {
        int add = (t >= off) ? s[t - off] : 0;
        __syncthreads();
        s[t] += add;
        __syncthreads();
    }
    if (t < nb) bsum[t] = s[t] - v;   // exclusive
}

__global__ __launch_bounds__(256) void scan_write_kernel(
    const int* __restrict__ counts, const int* __restrict__ bsum,
    int* __restrict__ out, int len)
{
    __shared__ int s[256];
    const int t    = threadIdx.x;
    const int base = blockIdx.x * SCAN_CHUNK + t * 8;
    int c[8], ex[8], run = 0;
#pragma unroll
    for (int j = 0; j < 8; ++j) {
        const int idx = base + j;
        c[j] = (idx < len) ? counts[idx] : 0;
        ex[j] = run; run += c[j];
    }
    s[t] = run; __syncthreads();
    for (int off = 1; off < 256; off <<= 1) {
        int add = (t >= off) ? s[t - off] : 0;
        __syncthreads();
        s[t] += add;
        __syncthreads();
    }
    const int thread_base = bsum[blockIdx.x] + s[t] - run;
#pragma unroll
    for (int j = 0; j < 8; ++j) {
        const int idx = base + j;
        if (idx < len) out[idx] = thread_base + ex[j];
    }
}

// ---------------------------------------------------------------------------
// Pass A1: per-(bucket,segment) histogram.
// ---------------------------------------------------------------------------
__global__ __launch_bounds__(256) void seg_hist_kernel(
    const int* __restrict__ ei, int* __restrict__ counts_seg)
{
    __shared__ int h[KB_];
    const int s = blockIdx.x;
    for (int k = threadIdx.x; k < KB_; k += 256) h[k] = 0;
    __syncthreads();
    const int base = s * EPS;
    for (int i = threadIdx.x; i < EPS; i += 256) {
        const int dst = __builtin_nontemporal_load(&ei[EE + base + i]);
        atomicAdd(&h[dst >> 9], 1);
    }
    __syncthreads();
    for (int k = threadIdx.x; k < KB_; k += 256)
        counts_seg[k * GSEG + s] = h[k];
}

// ---------------------------------------------------------------------------
// Pass A2: append edges into bucket-grouped order.
// Record: x = src | dst_local<<18, y = w bits.
// ---------------------------------------------------------------------------
__global__ __launch_bounds__(256) void append_kernel(
    const int* __restrict__ ei, const float* __restrict__ ew,
    const int* __restrict__ bofs, int2* __restrict__ etmp)
{
    __shared__ int fr[KB_];
    const int s = blockIdx.x;
    for (int k = threadIdx.x; k < KB_; k += 256) fr[k] = bofs[k * GSEG + s];
    __syncthreads();
    const int base = s * EPS;
    for (int i = threadIdx.x; i < EPS; i += 256) {
        const int e   = base + i;
        const int   src = __builtin_nontemporal_load(&ei[e]);
        const int   dst = __builtin_nontemporal_load(&ei[EE + e]);
        const float w   = __builtin_nontemporal_load(&ew[e]);
        const int k  = dst >> 9;
        const int dl = dst & 511;
        const int pos = atomicAdd(&fr[k], 1);   // LDS atomic
        etmp[pos] = make_int2(src | (dl << 18), __float_as_int(w));
    }
}

// ---------------------------------------------------------------------------
// Pass B: exact dst-sort within each bucket + row_ptr construction.
// Output record: x = src*128 (byte offset into fp16 table), y = w bits.
// ---------------------------------------------------------------------------
__global__ __launch_bounds__(256) void bucket_sort_kernel(
    const int2* __restrict__ etmp, const int* __restrict__ bofs,
    int2* __restrict__ edges, int* __restrict__ row_ptr)
{
    __shared__ int cnt[512];
    __shared__ int cur[512];
    __shared__ int part[256];
    const int k = blockIdx.x;
    const int t = threadIdx.x;
    cnt[t] = 0; cnt[t + 256] = 0;
    __syncthreads();
    const int beg = bofs[k * GSEG];
    const int end = (k == KB_ - 1) ? EE : bofs[(k + 1) * GSEG];
    for (int e = beg + t; e < end; e += 256)
        atomicAdd(&cnt[((unsigned)etmp[e].x) >> 18], 1);
    __syncthreads();
    const int c0 = cnt[2 * t], c1 = cnt[2 * t + 1];
    const int run = c0 + c1;
    part[t] = run; __syncthreads();
    for (int off = 1; off < 256; off <<= 1) {
        int add = (t >= off) ? part[t - off] : 0;
        __syncthreads();
        part[t] += add;
        __syncthreads();
    }
    const int base = beg + part[t] - run;         // exclusive prefix + bucket base
    cur[2 * t]     = base;
    cur[2 * t + 1] = base + c0;
    const int node0 = (k << 9) + 2 * t;
    if (node0 < NN)     row_ptr[node0]     = base;
    if (node0 + 1 < NN) row_ptr[node0 + 1] = base + c0;
    if (k == KB_ - 1 && t == 0) row_ptr[NN] = EE;
    __syncthreads();
    for (int e = beg + t; e < end; e += 256) {
        const int2 r  = etmp[e];
        const int  dl = ((unsigned)r.x) >> 18;
        const int  pos = atomicAdd(&cur[dl], 1);  // LDS atomic
        edges[pos] = make_int2((r.x & 0x3FFFF) << 7, r.y);   // src byte-offset
    }
}

// ---------------------------------------------------------------------------
// fp32 embeddings -> fp16 gather table xh [N][64]
// ---------------------------------------------------------------------------
__global__ __launch_bounds__(256) void convert_x_kernel(
    const float* __restrict__ xu, const float* __restrict__ xi,
    _Float16* __restrict__ xh)
{
    const int i = blockIdx.x * 256 + threadIdx.x;
    if (i >= NN * DD / 4) return;
    const float4 v = (i < NUM_USERS * DD / 4)
                       ? ((const float4*)xu)[i]
                       : ((const float4*)xi)[i - NUM_USERS * DD / 4];
    half4 o; o[0] = (_Float16)v.x; o[1] = (_Float16)v.y;
             o[2] = (_Float16)v.z; o[3] = (_Float16)v.w;
    ((half4*)xh)[i] = o;
}

// W [k][n] fp32 -> Wt [n][k] fp16
__global__ __launch_bounds__(256) void convert_w_kernel(
    const float* __restrict__ W1, const float* __restrict__ W2,
    _Float16* __restrict__ Wt)
{
    const int idx = blockIdx.x * 256 + threadIdx.x;
    if (idx >= 2 * DD * DD) return;
    const int mat = idx >> 12, rem = idx & 4095, k = rem >> 6, n = rem & 63;
    const float* W = mat ? W2 : W1;
    Wt[mat * DD * DD + n * DD + k] = (_Float16)W[k * DD + n];
}

// ---------------------------------------------------------------------------
// Aggregation v4: one wave per FOUR adjacent rows; the wave's edge range
// [row_ptr[n0], row_ptr[n0+4]) is CONTIGUOUS and walked edge-centrically in
// groups of 8 with a two-group double buffer:
//   - records are wave-uniform -> scalar s_loads (SGPRs)
//   - gathers for group i+1 issue before the FMAs of group i -> constant
//     16 gathers in flight for EVERY edge (no min-of-streams, no drains)
//   - row assignment resolved scalar-side: sel = #row-bounds crossed.
//     Groups w/o a boundary (~60%) take a uniform branch into a straight
//     8-FMA block; boundary/tail groups use branchless 4-slot predicated FMA.
// Round-2 lesson kept: all loads plain cached (no nt).
// ---------------------------------------------------------------------------

// load 8 records (scalar) + issue 8 gathers; indices clamped to [0, end-1]
#define LOADG(r, h, basev)                                                   \
  do {                                                                       \
    _Pragma("unroll")                                                        \
    for (int j = 0; j < 8; ++j) {                                            \
      int idx = (basev) + j;                                                 \
      idx = idx < end ? idx : end - 1;                                       \
      idx = idx > 0 ? idx : 0;                                               \
      r[j] = edges[idx];                                                     \
      h[j] = *(const _Float16*)(xb + (unsigned)r[j].x + lane2);              \
    }                                                                        \
  } while (0)

#define FMA8(r, h, a)                                                        \
  do {                                                                       \
    _Pragma("unroll")                                                        \
    for (int j = 0; j < 8; ++j)                                              \
      a = fmaf(__int_as_float(r[j].y), (float)h[j], a);                      \
  } while (0)

#define PROCESS(r, h, basev)                                                 \
  do {                                                                       \
    const int selL = ((basev) >= f0) + ((basev) >= f1) + ((basev) >= f2);    \
    const int selH = ((basev) + 7 >= f0) + ((basev) + 7 >= f1) +             \
                     ((basev) + 7 >= f2);                                    \
    if (selL == selH && (basev) + 8 <= end) {                                \
      if      (selL == 0) { FMA8(r, h, acc0); }                              \
      else if (selL == 1) { FMA8(r, h, acc1); }                              \
      else if (selL == 2) { FMA8(r, h, acc2); }                              \
      else                { FMA8(r, h, acc3); }                              \
    } else {                                                                 \
      _Pragma("unroll")                                                      \
      for (int j = 0; j < 8; ++j) {                                          \
        const int idx = (basev) + j;                                         \
        float w = __int_as_float(r[j].y);                                    \
        w = (idx < end) ? w : 0.0f;                                          \
        const int sel = (idx >= f0) + (idx >= f1) + (idx >= f2);             \
        const float hv = (float)h[j];                                        \
        acc0 = fmaf((sel == 0) ? w : 0.0f, hv, acc0);                        \
        acc1 = fmaf((sel == 1) ? w : 0.0f, hv, acc1);                        \
        acc2 = fmaf((sel == 2) ? w : 0.0f, hv, acc2);                        \
        acc3 = fmaf((sel == 3) ? w : 0.0f, hv, acc3);                        \
      }                                                                      \
    }                                                                        \
  } while (0)

__global__ __launch_bounds__(256) void aggregate_kernel(
    const int2* __restrict__ edges, const int* __restrict__ row_ptr,
    const _Float16* __restrict__ xh, _Float16* __restrict__ u)
{
    const int wave = (blockIdx.x * 256 + threadIdx.x) >> 6;  // 0..49999
    const int lane = threadIdx.x & 63;
    const unsigned lane2 = lane * 2;
    const int nbase = wave * 4;
    const char* xb = (const char*)xh;

    const int beg = __builtin_amdgcn_readfirstlane(row_ptr[nbase + 0]);
    const int f0  = __builtin_amdgcn_readfirstlane(row_ptr[nbase + 1]);
    const int f1  = __builtin_amdgcn_readfirstlane(row_ptr[nbase + 2]);
    const int f2  = __builtin_amdgcn_readfirstlane(row_ptr[nbase + 3]);
    const int end = __builtin_amdgcn_readfirstlane(row_ptr[nbase + 4]);

    float acc0 = (float)*(const _Float16*)(xb + ((unsigned)(nbase + 0) << 7) + lane2);
    float acc1 = (float)*(const _Float16*)(xb + ((unsigned)(nbase + 1) << 7) + lane2);
    float acc2 = (float)*(const _Float16*)(xb + ((unsigned)(nbase + 2) << 7) + lane2);
    float acc3 = (float)*(const _Float16*)(xb + ((unsigned)(nbase + 3) << 7) + lane2);

    int2     rA[8], rB[8];
    _Float16 hA[8], hB[8];

    int g = beg;
    LOADG(rA, hA, g);
    LOADG(rB, hB, g + 8);
    while (g < end) {
        PROCESS(rA, hA, g);
        if (g + 16 < end) LOADG(rA, hA, g + 16);
        g += 8;
        if (g >= end) break;
        PROCESS(rB, hB, g);
        if (g + 16 < end) LOADG(rB, hB, g + 16);
        g += 8;
    }

    char* ub = (char*)u;
    *(_Float16*)(ub + ((unsigned)(nbase + 0) << 7) + lane2) = (_Float16)(acc0 * 0.5f);
    *(_Float16*)(ub + ((unsigned)(nbase + 1) << 7) + lane2) = (_Float16)(acc1 * 0.5f);
    *(_Float16*)(ub + ((unsigned)(nbase + 2) << 7) + lane2) = (_Float16)(acc2 * 0.5f);
    *(_Float16*)(ub + ((unsigned)(nbase + 3) << 7) + lane2) = (_Float16)(acc3 * 0.5f);
}

// ---------------------------------------------------------------------------
// GEMM: out[N,64] = u[N,64] @ W[64,64] + b (unchanged)
// ---------------------------------------------------------------------------
template<bool HALF_OUT>
__global__ __launch_bounds__(256) void gemm64_kernel(
    const _Float16* __restrict__ u, const _Float16* __restrict__ Wt,
    const float* __restrict__ bias, void* __restrict__ outp)
{
    const int wid  = blockIdx.x * 4 + (threadIdx.x >> 6);
    const int lane = threadIdx.x & 63;
    const int m    = lane & 15;
    const int quad = lane >> 4;
    const size_t rowbase = (size_t)wid * 16;

    half8 bf[4][2];
#pragma unroll
    for (int c = 0; c < 4; ++c)
#pragma unroll
        for (int h = 0; h < 2; ++h)
            bf[c][h] = *(const half8*)(Wt + (size_t)(c * 16 + m) * DD + h * 32 + quad * 8);

    const half8 a0 = *(const half8*)(u + (rowbase + m) * DD +  0 + quad * 8);
    const half8 a1 = *(const half8*)(u + (rowbase + m) * DD + 32 + quad * 8);

    f32x4 acc[4];
#pragma unroll
    for (int c = 0; c < 4; ++c) {
        f32x4 z = {0.f, 0.f, 0.f, 0.f};
        z = __builtin_amdgcn_mfma_f32_16x16x32_f16(a0, bf[c][0], z, 0, 0, 0);
        z = __builtin_amdgcn_mfma_f32_16x16x32_f16(a1, bf[c][1], z, 0, 0, 0);
        acc[c] = z;
    }

#pragma unroll
    for (int c = 0; c < 4; ++c) {
        const float bv = bias[c * 16 + m];
#pragma unroll
        for (int r = 0; r < 4; ++r) {
            const size_t row = rowbase + quad * 4 + r;
            const float val = acc[c][r] + bv;
            if (HALF_OUT) ((_Float16*)outp)[row * DD + c * 16 + m] = (_Float16)val;
            else          ((float*)    outp)[row * DD + c * 16 + m] = val;
        }
    }
}

extern "C" void kernel_launch(void* const* d_in, const int* in_sizes, int n_in,
                              void* d_out, int out_size, void* d_ws, size_t ws_size,
                              hipStream_t stream) {
    const int*   edge_index  = (const int*)  d_in[0];
    const float* edge_weight = (const float*)d_in[1];
    const float* user_emb    = (const float*)d_in[2];
    const float* item_emb    = (const float*)d_in[3];
    const float* W1          = (const float*)d_in[4];
    const float* b1          = (const float*)d_in[5];
    const float* W2          = (const float*)d_in[6];
    const float* b2          = (const float*)d_in[7];
    float*       out         = (float*)d_out;

    // Workspace layout:
    char* ws = (char*)d_ws;
    _Float16* xh        = (_Float16*)(ws);               // 25,600,000 B (h1 aliases after layer 1)
    _Float16* u         = (_Float16*)(ws + 25600000);    // 25,600,000 B — also etmp during build
    int2*     etmp      = (int2*)    (ws + 25600000);    //   (alias of u)
    int2*     edges     = (int2*)    (ws + 51200000);    // 25,600,000 B (dst-sorted)
    int*      row_ptr   = (int*)     (ws + 76800000);    //    800,064 B
    int*      cseg      = (int*)     (ws + 78400064);    //    800,768 B (MSEG counters)
    int*      bofs      = (int*)     (ws + 79200832);    //    800,768 B (scanned MSEG)
    int*      bsum      = (int*)     (ws + 80001600);    //        512 B
    _Float16* Wt        = (_Float16*)(ws + 80002112);    //     16,384 B

    const int gemm_blocks = (NN / 16) / 4;               // 3125
    const int agg_blocks  = NN / 16;                     // 12500 (4 nodes/wave, 4 waves/block)

    // ---- bucket partition (segment-level scan) ----
    seg_hist_kernel     <<<GSEG,    256, 0, stream>>>(edge_index, cseg);
    scan_partials_kernel<<<NB_SCAN, 256, 0, stream>>>(cseg, bsum, MSEG);
    scan_top_kernel     <<<1,       128, 0, stream>>>(bsum, NB_SCAN);
    scan_write_kernel   <<<NB_SCAN, 256, 0, stream>>>(cseg, bsum, bofs, MSEG);

    // ---- append into buckets, then exact sort (also builds row_ptr) ----
    append_kernel      <<<GSEG, 256, 0, stream>>>(edge_index, edge_weight, bofs, etmp);
    bucket_sort_kernel <<<KB_,  256, 0, stream>>>(etmp, bofs, edges, row_ptr);

    // ---- fp16 conversions ----
    convert_x_kernel<<<(NN * DD / 4 + 255) / 256, 256, 0, stream>>>(user_emb, item_emb, xh);
    convert_w_kernel<<<(2 * DD * DD + 255) / 256, 256, 0, stream>>>(W1, W2, Wt);

    // ---- Layer 1 ----
    aggregate_kernel<<<agg_blocks, 256, 0, stream>>>(edges, row_ptr, xh, u);
    gemm64_kernel<true><<<gemm_blocks, 256, 0, stream>>>(u, Wt, b1, (void*)xh);

    // ---- Layer 2 ----
    aggregate_kernel<<<agg_blocks, 256, 0, stream>>>(edges, row_ptr, xh, u);
    gemm64_kernel<false><<<gemm_blocks, 256, 0, stream>>>(u, Wt + DD * DD, b2, (void*)out);
}

// Round 4
// 518.001 us; speedup vs baseline: 1.0570x; 1.0570x over previous
//
#include <hip/hip_runtime.h>
#include <hip/hip_fp16.h>

#define NUM_USERS 100000
#define NN        200000          // N = users + items
#define DD        64
#define EE        3200000
#define SCAN_CHUNK 2048
#define NB_SCAN   98              // covers up to 200704 elements

#define KB_   391                 // dst buckets: 512 nodes each (dst >> 9)
#define GSEG  512                 // edge segments
#define EPS   (EE / GSEG)         // 6250 edges per segment
#define MSEG  (KB_ * GSEG)        // 200192 (bucket,segment) counters

typedef _Float16 half8 __attribute__((ext_vector_type(8)));
typedef _Float16 half4 __attribute__((ext_vector_type(4)));
typedef float    f32x4 __attribute__((ext_vector_type(4)));

// ---------------------------------------------------------------------------
// Generic 3-phase exclusive scan (len <= NB_SCAN*SCAN_CHUNK).
// ---------------------------------------------------------------------------
__global__ __launch_bounds__(256) void scan_partials_kernel(
    const int* __restrict__ counts, int* __restrict__ bsum, int len)
{
    __shared__ int s[256];
    const int t = threadIdx.x;
    int sum = 0;
    for (int i = t; i < SCAN_CHUNK; i += 256) {
        const int idx = blockIdx.x * SCAN_CHUNK + i;
        sum += (idx < len) ? counts[idx] : 0;
    }
    s[t] = sum; __syncthreads();
    for (int off = 128; off > 0; off >>= 1) {
        if (t < off) s[t] += s[t + off];
        __syncthreads();
    }
    if (t == 0) bsum[blockIdx.x] = s[0];
}

__global__ __launch_bounds__(128) void scan_top_kernel(int* __restrict__ bsum, int nb)
{
    __shared__ int s[128];
    const int t = threadIdx.x;
    const int v = (t < nb) ? bsum[t] : 0;
    s[t] = v; __syncthreads();
    for (int off = 1; off < 128; off <<= 1) {
        int add = (t >= off) ? s[t - off] : 0;
        __syncthreads();
        s[t] += add;
        __syncthreads();
    }
    if (t < nb) bsum[t] = s[t] - v;   // exclusive
}

__global__ __launch_bounds__(256) void scan_write_kernel(
    const int* __restrict__ counts, const int* __restrict__ bsum,
    int* __restrict__ out, int len)
{
    __shared__ int s[256];
    const int t    = threadIdx.x;
    const int base = blockIdx.x * SCAN_CHUNK + t * 8;
    int c[8], ex[8], run = 0;
#pragma unroll
    for (int j = 0; j < 8; ++j) {
        const int idx = base + j;
        c[j] = (idx < len) ? counts[idx] : 0;
        ex[j] = run; run += c[j];
    }
    s[t] = run; __syncthreads();
    for (int off = 1; off < 256; off <<= 1) {
        int add = (t >= off) ? s[t - off] : 0;
        __syncthreads();
        s[t] += add;
        __syncthreads();
    }
    const int thread_base = bsum[blockIdx.x] + s[t] - run;
#pragma unroll
    for (int j = 0; j < 8; ++j) {
        const int idx = base + j;
        if (idx < len) out[idx] = thread_base + ex[j];
    }
}

// ---------------------------------------------------------------------------
// Pass A1: per-(bucket,segment) histogram.
// ---------------------------------------------------------------------------
__global__ __launch_bounds__(256) void seg_hist_kernel(
    const int* __restrict__ ei, int* __restrict__ counts_seg)
{
    __shared__ int h[KB_];
    const int s = blockIdx.x;
    for (int k = threadIdx.x; k < KB_; k += 256) h[k] = 0;
    __syncthreads();
    const int base = s * EPS;
    for (int i = threadIdx.x; i < EPS; i += 256) {
        const int dst = __builtin_nontemporal_load(&ei[EE + base + i]);
        atomicAdd(&h[dst >> 9], 1);
    }
    __syncthreads();
    for (int k = threadIdx.x; k < KB_; k += 256)
        counts_seg[k * GSEG + s] = h[k];
}

// ---------------------------------------------------------------------------
// Pass A2: append edges into bucket-grouped order.
// Record: x = src | dst_local<<18, y = w bits.
// ---------------------------------------------------------------------------
__global__ __launch_bounds__(256) void append_kernel(
    const int* __restrict__ ei, const float* __restrict__ ew,
    const int* __restrict__ bofs, int2* __restrict__ etmp)
{
    __shared__ int fr[KB_];
    const int s = blockIdx.x;
    for (int k = threadIdx.x; k < KB_; k += 256) fr[k] = bofs[k * GSEG + s];
    __syncthreads();
    const int base = s * EPS;
    for (int i = threadIdx.x; i < EPS; i += 256) {
        const int e   = base + i;
        const int   src = __builtin_nontemporal_load(&ei[e]);
        const int   dst = __builtin_nontemporal_load(&ei[EE + e]);
        const float w   = __builtin_nontemporal_load(&ew[e]);
        const int k  = dst >> 9;
        const int dl = dst & 511;
        const int pos = atomicAdd(&fr[k], 1);   // LDS atomic
        etmp[pos] = make_int2(src | (dl << 18), __float_as_int(w));
    }
}

// ---------------------------------------------------------------------------
// Pass B: exact dst-sort within each bucket + row_ptr construction.
// Output record: x = src*128 (byte offset into fp16 table), y = w bits.
// ---------------------------------------------------------------------------
__global__ __launch_bounds__(256) void bucket_sort_kernel(
    const int2* __restrict__ etmp, const int* __restrict__ bofs,
    int2* __restrict__ edges, int* __restrict__ row_ptr)
{
    __shared__ int cnt[512];
    __shared__ int cur[512];
    __shared__ int part[256];
    const int k = blockIdx.x;
    const int t = threadIdx.x;
    cnt[t] = 0; cnt[t + 256] = 0;
    __syncthreads();
    const int beg = bofs[k * GSEG];
    const int end = (k == KB_ - 1) ? EE : bofs[(k + 1) * GSEG];
    for (int e = beg + t; e < end; e += 256)
        atomicAdd(&cnt[((unsigned)etmp[e].x) >> 18], 1);
    __syncthreads();
    const int c0 = cnt[2 * t], c1 = cnt[2 * t + 1];
    const int run = c0 + c1;
    part[t] = run; __syncthreads();
    for (int off = 1; off < 256; off <<= 1) {
        int add = (t >= off) ? part[t - off] : 0;
        __syncthreads();
        part[t] += add;
        __syncthreads();
    }
    const int base = beg + part[t] - run;         // exclusive prefix + bucket base
    cur[2 * t]     = base;
    cur[2 * t + 1] = base + c0;
    const int node0 = (k << 9) + 2 * t;
    if (node0 < NN)     row_ptr[node0]     = base;
    if (node0 + 1 < NN) row_ptr[node0 + 1] = base + c0;
    if (k == KB_ - 1 && t == 0) row_ptr[NN] = EE;
    __syncthreads();
    for (int e = beg + t; e < end; e += 256) {
        const int2 r  = etmp[e];
        const int  dl = ((unsigned)r.x) >> 18;
        const int  pos = atomicAdd(&cur[dl], 1);  // LDS atomic
        edges[pos] = make_int2((r.x & 0x3FFFF) << 7, r.y);   // src byte-offset
    }
}

// ---------------------------------------------------------------------------
// fp32 embeddings -> fp16 gather table xh [N][64]
// ---------------------------------------------------------------------------
__global__ __launch_bounds__(256) void convert_x_kernel(
    const float* __restrict__ xu, const float* __restrict__ xi,
    _Float16* __restrict__ xh)
{
    const int i = blockIdx.x * 256 + threadIdx.x;
    if (i >= NN * DD / 4) return;
    const float4 v = (i < NUM_USERS * DD / 4)
                       ? ((const float4*)xu)[i]
                       : ((const float4*)xi)[i - NUM_USERS * DD / 4];
    half4 o; o[0] = (_Float16)v.x; o[1] = (_Float16)v.y;
             o[2] = (_Float16)v.z; o[3] = (_Float16)v.w;
    ((half4*)xh)[i] = o;
}

// W [k][n] fp32 -> Wt [n][k] fp16
__global__ __launch_bounds__(256) void convert_w_kernel(
    const float* __restrict__ W1, const float* __restrict__ W2,
    _Float16* __restrict__ Wt)
{
    const int idx = blockIdx.x * 256 + threadIdx.x;
    if (idx >= 2 * DD * DD) return;
    const int mat = idx >> 12, rem = idx & 4095, k = rem >> 6, n = rem & 63;
    const float* W = mat ? W2 : W1;
    Wt[mat * DD * DD + n * DD + k] = (_Float16)W[k * DD + n];
}

// ---------------------------------------------------------------------------
// Aggregation v5: v3 skeleton (4 rows/wave, 4 streams x 4-deep, scalar
// records via readfirstlane'd uniform indices, plain cached loads) but ONE
// fused loop instead of steady-state + sequential drains:
//   every iteration processes 4 slots from EACH stream; exhausted streams
//   get scalar-clamped indices (same-address L1-hit gathers) and a single
//   zero-weight select per slot. One FMA per slot — no v4-style 4-way
//   predication. Every real edge runs at the full 16-deep gather MLP.
// ---------------------------------------------------------------------------
__global__ __launch_bounds__(256) void aggregate_kernel(
    const int2* __restrict__ edges, const int* __restrict__ row_ptr,
    const _Float16* __restrict__ xh, _Float16* __restrict__ u)
{
    const int wave = (blockIdx.x * 256 + threadIdx.x) >> 6;  // 0..49999
    const int lane = threadIdx.x & 63;
    const unsigned lane2 = lane * 2;
    const int nbase = wave * 4;
    const char* xb = (const char*)xh;

    int e0 = __builtin_amdgcn_readfirstlane(row_ptr[nbase + 0]);
    const int f0 = __builtin_amdgcn_readfirstlane(row_ptr[nbase + 1]);
    const int f1 = __builtin_amdgcn_readfirstlane(row_ptr[nbase + 2]);
    const int f2 = __builtin_amdgcn_readfirstlane(row_ptr[nbase + 3]);
    const int f3 = __builtin_amdgcn_readfirstlane(row_ptr[nbase + 4]);
    int e1 = f0, e2 = f1, e3 = f2;

    float acc0 = (float)*(const _Float16*)(xb + ((unsigned)(nbase + 0) << 7) + lane2);
    float acc1 = (float)*(const _Float16*)(xb + ((unsigned)(nbase + 1) << 7) + lane2);
    float acc2 = (float)*(const _Float16*)(xb + ((unsigned)(nbase + 2) << 7) + lane2);
    float acc3 = (float)*(const _Float16*)(xb + ((unsigned)(nbase + 3) << 7) + lane2);

    while ((e0 < f0) || (e1 < f1) || (e2 < f2) || (e3 < f3)) {
        int2  rec[16];
        float wv[16];
        _Float16 hv[16];

        // ---- phase 1: 16 record s_loads + 16 gathers issued back-to-back ----
#pragma unroll
        for (int j = 0; j < 4; ++j) {
            int idx = e0 + j;
            const bool ok = idx < f0;
            idx = ok ? idx : f0 - 1;
            idx = idx > 0 ? idx : 0;
            rec[j] = edges[idx];
            hv[j] = *(const _Float16*)(xb + (unsigned)rec[j].x + lane2);
            wv[j] = ok ? __int_as_float(rec[j].y) : 0.0f;
        }
#pragma unroll
        for (int j = 0; j < 4; ++j) {
            int idx = e1 + j;
            const bool ok = idx < f1;
            idx = ok ? idx : f1 - 1;
            idx = idx > 0 ? idx : 0;
            rec[4 + j] = edges[idx];
            hv[4 + j] = *(const _Float16*)(xb + (unsigned)rec[4 + j].x + lane2);
            wv[4 + j] = ok ? __int_as_float(rec[4 + j].y) : 0.0f;
        }
#pragma unroll
        for (int j = 0; j < 4; ++j) {
            int idx = e2 + j;
            const bool ok = idx < f2;
            idx = ok ? idx : f2 - 1;
            idx = idx > 0 ? idx : 0;
            rec[8 + j] = edges[idx];
            hv[8 + j] = *(const _Float16*)(xb + (unsigned)rec[8 + j].x + lane2);
            wv[8 + j] = ok ? __int_as_float(rec[8 + j].y) : 0.0f;
        }
#pragma unroll
        for (int j = 0; j < 4; ++j) {
            int idx = e3 + j;
            const bool ok = idx < f3;
            idx = ok ? idx : f3 - 1;
            idx = idx > 0 ? idx : 0;
            rec[12 + j] = edges[idx];
            hv[12 + j] = *(const _Float16*)(xb + (unsigned)rec[12 + j].x + lane2);
            wv[12 + j] = ok ? __int_as_float(rec[12 + j].y) : 0.0f;
        }

        // ---- phase 2: 16 FMAs ----
#pragma unroll
        for (int j = 0; j < 4; ++j) acc0 = fmaf(wv[j],      (float)hv[j],      acc0);
#pragma unroll
        for (int j = 0; j < 4; ++j) acc1 = fmaf(wv[4 + j],  (float)hv[4 + j],  acc1);
#pragma unroll
        for (int j = 0; j < 4; ++j) acc2 = fmaf(wv[8 + j],  (float)hv[8 + j],  acc2);
#pragma unroll
        for (int j = 0; j < 4; ++j) acc3 = fmaf(wv[12 + j], (float)hv[12 + j], acc3);

        e0 += 4; e1 += 4; e2 += 4; e3 += 4;
    }

    char* ub = (char*)u;
    *(_Float16*)(ub + ((unsigned)(nbase + 0) << 7) + lane2) = (_Float16)(acc0 * 0.5f);
    *(_Float16*)(ub + ((unsigned)(nbase + 1) << 7) + lane2) = (_Float16)(acc1 * 0.5f);
    *(_Float16*)(ub + ((unsigned)(nbase + 2) << 7) + lane2) = (_Float16)(acc2 * 0.5f);
    *(_Float16*)(ub + ((unsigned)(nbase + 3) << 7) + lane2) = (_Float16)(acc3 * 0.5f);
}

// ---------------------------------------------------------------------------
// GEMM: out[N,64] = u[N,64] @ W[64,64] + b (unchanged)
// ---------------------------------------------------------------------------
template<bool HALF_OUT>
__global__ __launch_bounds__(256) void gemm64_kernel(
    const _Float16* __restrict__ u, const _Float16* __restrict__ Wt,
    const float* __restrict__ bias, void* __restrict__ outp)
{
    const int wid  = blockIdx.x * 4 + (threadIdx.x >> 6);
    const int lane = threadIdx.x & 63;
    const int m    = lane & 15;
    const int quad = lane >> 4;
    const size_t rowbase = (size_t)wid * 16;

    half8 bf[4][2];
#pragma unroll
    for (int c = 0; c < 4; ++c)
#pragma unroll
        for (int h = 0; h < 2; ++h)
            bf[c][h] = *(const half8*)(Wt + (size_t)(c * 16 + m) * DD + h * 32 + quad * 8);

    const half8 a0 = *(const half8*)(u + (rowbase + m) * DD +  0 + quad * 8);
    const half8 a1 = *(const half8*)(u + (rowbase + m) * DD + 32 + quad * 8);

    f32x4 acc[4];
#pragma unroll
    for (int c = 0; c < 4; ++c) {
        f32x4 z = {0.f, 0.f, 0.f, 0.f};
        z = __builtin_amdgcn_mfma_f32_16x16x32_f16(a0, bf[c][0], z, 0, 0, 0);
        z = __builtin_amdgcn_mfma_f32_16x16x32_f16(a1, bf[c][1], z, 0, 0, 0);
        acc[c] = z;
    }

#pragma unroll
    for (int c = 0; c < 4; ++c) {
        const float bv = bias[c * 16 + m];
#pragma unroll
        for (int r = 0; r < 4; ++r) {
            const size_t row = rowbase + quad * 4 + r;
            const float val = acc[c][r] + bv;
            if (HALF_OUT) ((_Float16*)outp)[row * DD + c * 16 + m] = (_Float16)val;
            else          ((float*)    outp)[row * DD + c * 16 + m] = val;
        }
    }
}

extern "C" void kernel_launch(void* const* d_in, const int* in_sizes, int n_in,
                              void* d_out, int out_size, void* d_ws, size_t ws_size,
                              hipStream_t stream) {
    const int*   edge_index  = (const int*)  d_in[0];
    const float* edge_weight = (const float*)d_in[1];
    const float* user_emb    = (const float*)d_in[2];
    const float* item_emb    = (const float*)d_in[3];
    const float* W1          = (const float*)d_in[4];
    const float* b1          = (const float*)d_in[5];
    const float* W2          = (const float*)d_in[6];
    const float* b2          = (const float*)d_in[7];
    float*       out         = (float*)d_out;

    // Workspace layout:
    char* ws = (char*)d_ws;
    _Float16* xh        = (_Float16*)(ws);               // 25,600,000 B (h1 aliases after layer 1)
    _Float16* u         = (_Float16*)(ws + 25600000);    // 25,600,000 B — also etmp during build
    int2*     etmp      = (int2*)    (ws + 25600000);    //   (alias of u)
    int2*     edges     = (int2*)    (ws + 51200000);    // 25,600,000 B (dst-sorted)
    int*      row_ptr   = (int*)     (ws + 76800000);    //    800,064 B
    int*      cseg      = (int*)     (ws + 78400064);    //    800,768 B (MSEG counters)
    int*      bofs      = (int*)     (ws + 79200832);    //    800,768 B (scanned MSEG)
    int*      bsum      = (int*)     (ws + 80001600);    //        512 B
    _Float16* Wt        = (_Float16*)(ws + 80002112);    //     16,384 B

    const int gemm_blocks = (NN / 16) / 4;               // 3125
    const int agg_blocks  = NN / 16;                     // 12500 (4 nodes/wave, 4 waves/block)

    // ---- bucket partition (segment-level scan) ----
    seg_hist_kernel     <<<GSEG,    256, 0, stream>>>(edge_index, cseg);
    scan_partials_kernel<<<NB_SCAN, 256, 0, stream>>>(cseg, bsum, MSEG);
    scan_top_kernel     <<<1,       128, 0, stream>>>(bsum, NB_SCAN);
    scan_write_kernel   <<<NB_SCAN, 256, 0, stream>>>(cseg, bsum, bofs, MSEG);

    // ---- append into buckets, then exact sort (also builds row_ptr) ----
    append_kernel      <<<GSEG, 256, 0, stream>>>(edge_index, edge_weight, bofs, etmp);
    bucket_sort_kernel <<<KB_,  256, 0, stream>>>(etmp, bofs, edges, row_ptr);

    // ---- fp16 conversions ----
    convert_x_kernel<<<(NN * DD / 4 + 255) / 256, 256, 0, stream>>>(user_emb, item_emb, xh);
    convert_w_kernel<<<(2 * DD * DD + 255) / 256, 256, 0, stream>>>(W1, W2, Wt);

    // ---- Layer 1 ----
    aggregate_kernel<<<agg_blocks, 256, 0, stream>>>(edges, row_ptr, xh, u);
    gemm64_kernel<true><<<gemm_blocks, 256, 0, stream>>>(u, Wt, b1, (void*)xh);

    // ---- Layer 2 ----
    aggregate_kernel<<<agg_blocks, 256, 0, stream>>>(edges, row_ptr, xh, u);
    gemm64_kernel<false><<<gemm_blocks, 256, 0, stream>>>(u, Wt + DD * DD, b2, (void*)out);
}

// Round 5
// 499.565 us; speedup vs baseline: 1.0960x; 1.0369x over previous
//
#include <hip/hip_runtime.h>
#include <hip/hip_fp16.h>

#define NUM_USERS 100000
#define NN        200000          // N = users + items
#define DD        64
#define EE        3200000
#define SCAN_CHUNK 2048
#define NB_SCAN   98              // covers up to 200704 elements

#define KB_   391                 // dst buckets: 512 nodes each (dst >> 9)
#define GSEG  512                 // edge segments
#define EPS   (EE / GSEG)         // 6250 edges per segment
#define MSEG  (KB_ * GSEG)        // 200192 (bucket,segment) counters

typedef _Float16 half8 __attribute__((ext_vector_type(8)));
typedef _Float16 half4 __attribute__((ext_vector_type(4)));
typedef float    f32x4 __attribute__((ext_vector_type(4)));

// ---------------------------------------------------------------------------
// Generic 3-phase exclusive scan (len <= NB_SCAN*SCAN_CHUNK).
// ---------------------------------------------------------------------------
__global__ __launch_bounds__(256) void scan_partials_kernel(
    const int* __restrict__ counts, int* __restrict__ bsum, int len)
{
    __shared__ int s[256];
    const int t = threadIdx.x;
    int sum = 0;
    for (int i = t; i < SCAN_CHUNK; i += 256) {
        const int idx = blockIdx.x * SCAN_CHUNK + i;
        sum += (idx < len) ? counts[idx] : 0;
    }
    s[t] = sum; __syncthreads();
    for (int off = 128; off > 0; off >>= 1) {
        if (t < off) s[t] += s[t + off];
        __syncthreads();
    }
    if (t == 0) bsum[blockIdx.x] = s[0];
}

__global__ __launch_bounds__(128) void scan_top_kernel(int* __restrict__ bsum, int nb)
{
    __shared__ int s[128];
    const int t = threadIdx.x;
    const int v = (t < nb) ? bsum[t] : 0;
    s[t] = v; __syncthreads();
    for (int off = 1; off < 128; off <<= 1) {
        int add = (t >= off) ? s[t - off] : 0;
        __syncthreads();
        s[t] += add;
        __syncthreads();
    }
    if (t < nb) bsum[t] = s[t] - v;   // exclusive
}

__global__ __launch_bounds__(256) void scan_write_kernel(
    const int* __restrict__ counts, const int* __restrict__ bsum,
    int* __restrict__ out, int len)
{
    __shared__ int s[256];
    const int t    = threadIdx.x;
    const int base = blockIdx.x * SCAN_CHUNK + t * 8;
    int c[8], ex[8], run = 0;
#pragma unroll
    for (int j = 0; j < 8; ++j) {
        const int idx = base + j;
        c[j] = (idx < len) ? counts[idx] : 0;
        ex[j] = run; run += c[j];
    }
    s[t] = run; __syncthreads();
    for (int off = 1; off < 256; off <<= 1) {
        int add = (t >= off) ? s[t - off] : 0;
        __syncthreads();
        s[t] += add;
        __syncthreads();
    }
    const int thread_base = bsum[blockIdx.x] + s[t] - run;
#pragma unroll
    for (int j = 0; j < 8; ++j) {
        const int idx = base + j;
        if (idx < len) out[idx] = thread_base + ex[j];
    }
}

// ---------------------------------------------------------------------------
// Pass A1: per-(bucket,segment) histogram.
// ---------------------------------------------------------------------------
__global__ __launch_bounds__(256) void seg_hist_kernel(
    const int* __restrict__ ei, int* __restrict__ counts_seg)
{
    __shared__ int h[KB_];
    const int s = blockIdx.x;
    for (int k = threadIdx.x; k < KB_; k += 256) h[k] = 0;
    __syncthreads();
    const int base = s * EPS;
    for (int i = threadIdx.x; i < EPS; i += 256) {
        const int dst = __builtin_nontemporal_load(&ei[EE + base + i]);
        atomicAdd(&h[dst >> 9], 1);
    }
    __syncthreads();
    for (int k = threadIdx.x; k < KB_; k += 256)
        counts_seg[k * GSEG + s] = h[k];
}

// ---------------------------------------------------------------------------
// Pass A2: append edges into bucket-grouped order.
// Record: x = src | dst_local<<18, y = w bits.
// ---------------------------------------------------------------------------
__global__ __launch_bounds__(256) void append_kernel(
    const int* __restrict__ ei, const float* __restrict__ ew,
    const int* __restrict__ bofs, int2* __restrict__ etmp)
{
    __shared__ int fr[KB_];
    const int s = blockIdx.x;
    for (int k = threadIdx.x; k < KB_; k += 256) fr[k] = bofs[k * GSEG + s];
    __syncthreads();
    const int base = s * EPS;
    for (int i = threadIdx.x; i < EPS; i += 256) {
        const int e   = base + i;
        const int   src = __builtin_nontemporal_load(&ei[e]);
        const int   dst = __builtin_nontemporal_load(&ei[EE + e]);
        const float w   = __builtin_nontemporal_load(&ew[e]);
        const int k  = dst >> 9;
        const int dl = dst & 511;
        const int pos = atomicAdd(&fr[k], 1);   // LDS atomic
        etmp[pos] = make_int2(src | (dl << 18), __float_as_int(w));
    }
}

// ---------------------------------------------------------------------------
// Pass B: exact dst-sort within each bucket + row_ptr construction.
// Output record: x = src*128 (byte offset into fp16 table), y = w bits.
// ---------------------------------------------------------------------------
__global__ __launch_bounds__(256) void bucket_sort_kernel(
    const int2* __restrict__ etmp, const int* __restrict__ bofs,
    int2* __restrict__ edges, int* __restrict__ row_ptr)
{
    __shared__ int cnt[512];
    __shared__ int cur[512];
    __shared__ int part[256];
    const int k = blockIdx.x;
    const int t = threadIdx.x;
    cnt[t] = 0; cnt[t + 256] = 0;
    __syncthreads();
    const int beg = bofs[k * GSEG];
    const int end = (k == KB_ - 1) ? EE : bofs[(k + 1) * GSEG];
    for (int e = beg + t; e < end; e += 256)
        atomicAdd(&cnt[((unsigned)etmp[e].x) >> 18], 1);
    __syncthreads();
    const int c0 = cnt[2 * t], c1 = cnt[2 * t + 1];
    const int run = c0 + c1;
    part[t] = run; __syncthreads();
    for (int off = 1; off < 256; off <<= 1) {
        int add = (t >= off) ? part[t - off] : 0;
        __syncthreads();
        part[t] += add;
        __syncthreads();
    }
    const int base = beg + part[t] - run;         // exclusive prefix + bucket base
    cur[2 * t]     = base;
    cur[2 * t + 1] = base + c0;
    const int node0 = (k << 9) + 2 * t;
    if (node0 < NN)     row_ptr[node0]     = base;
    if (node0 + 1 < NN) row_ptr[node0 + 1] = base + c0;
    if (k == KB_ - 1 && t == 0) row_ptr[NN] = EE;
    __syncthreads();
    for (int e = beg + t; e < end; e += 256) {
        const int2 r  = etmp[e];
        const int  dl = ((unsigned)r.x) >> 18;
        const int  pos = atomicAdd(&cur[dl], 1);  // LDS atomic
        edges[pos] = make_int2((r.x & 0x3FFFF) << 7, r.y);   // src byte-offset
    }
}

// ---------------------------------------------------------------------------
// fp32 embeddings -> fp16 gather table xh [N][64]
// ---------------------------------------------------------------------------
__global__ __launch_bounds__(256) void convert_x_kernel(
    const float* __restrict__ xu, const float* __restrict__ xi,
    _Float16* __restrict__ xh)
{
    const int i = blockIdx.x * 256 + threadIdx.x;
    if (i >= NN * DD / 4) return;
    const float4 v = (i < NUM_USERS * DD / 4)
                       ? ((const float4*)xu)[i]
                       : ((const float4*)xi)[i - NUM_USERS * DD / 4];
    half4 o; o[0] = (_Float16)v.x; o[1] = (_Float16)v.y;
             o[2] = (_Float16)v.z; o[3] = (_Float16)v.w;
    ((half4*)xh)[i] = o;
}

// W [k][n] fp32 -> Wt [n][k] fp16
__global__ __launch_bounds__(256) void convert_w_kernel(
    const float* __restrict__ W1, const float* __restrict__ W2,
    _Float16* __restrict__ Wt)
{
    const int idx = blockIdx.x * 256 + threadIdx.x;
    if (idx >= 2 * DD * DD) return;
    const int mat = idx >> 12, rem = idx & 4095, k = rem >> 6, n = rem & 63;
    const float* W = mat ? W2 : W1;
    Wt[mat * DD * DD + n * DD + k] = (_Float16)W[k * DD + n];
}

// ---------------------------------------------------------------------------
// Aggregation v6: QUARTER-WAVE = ROW layout. Wave owns 4 adjacent rows;
// quarter q (lanes 16q..16q+15) owns row nbase+q; lane holds dims 4i..4i+3
// as 4 fp32 accumulators. ONE dwordx2 gather instruction fetches the full
// source rows of FOUR edges (one per quarter, 16 lanes x 8B = one 128B line
// each) -> gather instruction count = E/4 instead of E.
// Rationale (v5 post-mortem): aggregate is bound by VMEM gather-instruction
// issue (time scaled with instruction count even for L1-hit duplicates),
// not by latency or cache lines. Records stay wave-uniform scalar loads
// with scalar clamps / scalar weight-zeroing; per-lane routing is a
// 3-cndmask select among the 4 scalar records. Exhausted quarters ride
// inside instructions that exist anyway -> tail waste ~free.
// ---------------------------------------------------------------------------
__global__ __launch_bounds__(256) void aggregate_kernel(
    const int2* __restrict__ edges, const int* __restrict__ row_ptr,
    const _Float16* __restrict__ xh, _Float16* __restrict__ u)
{
    const int wave = (blockIdx.x * 256 + threadIdx.x) >> 6;  // 0..49999
    const int lane = threadIdx.x & 63;
    const int nbase = wave * 4;
    const int q    = lane >> 4;          // quarter = row slot
    const int i16  = lane & 15;          // lane within quarter
    const unsigned qoff = (unsigned)i16 * 8;  // byte offset inside a row
    const char* xb = (const char*)xh;

    int e0 = __builtin_amdgcn_readfirstlane(row_ptr[nbase + 0]);
    const int f0 = __builtin_amdgcn_readfirstlane(row_ptr[nbase + 1]);
    const int f1 = __builtin_amdgcn_readfirstlane(row_ptr[nbase + 2]);
    const int f2 = __builtin_amdgcn_readfirstlane(row_ptr[nbase + 3]);
    const int f3 = __builtin_amdgcn_readfirstlane(row_ptr[nbase + 4]);
    int e1 = f0, e2 = f1, e3 = f2;

    // residual init: acc = x[own row], 4 dims per lane
    const unsigned rowb = ((unsigned)(nbase + q)) << 7;
    const half4 xi = *(const half4*)(xb + rowb + qoff);
    float a0 = (float)xi[0], a1 = (float)xi[1];
    float a2 = (float)xi[2], a3 = (float)xi[3];

    const bool lo32 = lane < 32;
    const bool loq  = (lane & 16) == 0;

    while ((e0 < f0) | (e1 < f1) | (e2 < f2) | (e3 < f3)) {
        int   bx[4];
        float ww[4];
        half4 hv[4];
#pragma unroll
        for (int j = 0; j < 4; ++j) {
            // scalar side: clamp indices, zero weights for exhausted quarters
            int i0 = e0 + j; const bool k0 = i0 < f0; i0 = k0 ? i0 : f0 - 1; i0 = i0 > 0 ? i0 : 0;
            int i1 = e1 + j; const bool k1 = i1 < f1; i1 = k1 ? i1 : f1 - 1; i1 = i1 > 0 ? i1 : 0;
            int i2 = e2 + j; const bool k2 = i2 < f2; i2 = k2 ? i2 : f2 - 1; i2 = i2 > 0 ? i2 : 0;
            int i3 = e3 + j; const bool k3 = i3 < f3; i3 = k3 ? i3 : f3 - 1; i3 = i3 > 0 ? i3 : 0;
            const int2 r0 = edges[i0];
            const int2 r1 = edges[i1];
            const int2 r2 = edges[i2];
            const int2 r3 = edges[i3];
            const float w0 = k0 ? __int_as_float(r0.y) : 0.0f;
            const float w1 = k1 ? __int_as_float(r1.y) : 0.0f;
            const float w2 = k2 ? __int_as_float(r2.y) : 0.0f;
            const float w3 = k3 ? __int_as_float(r3.y) : 0.0f;
            // per-lane routing: pick own quarter's record (3 cndmask each)
            bx[j] = lo32 ? (loq ? r0.x : r1.x) : (loq ? r2.x : r3.x);
            ww[j] = lo32 ? (loq ? w0 : w1) : (loq ? w2 : w3);
            // one gather instruction = 4 edges' rows (8B/lane)
            hv[j] = *(const half4*)(xb + (unsigned)bx[j] + qoff);
        }
#pragma unroll
        for (int j = 0; j < 4; ++j) {
            a0 = fmaf(ww[j], (float)hv[j][0], a0);
            a1 = fmaf(ww[j], (float)hv[j][1], a1);
            a2 = fmaf(ww[j], (float)hv[j][2], a2);
            a3 = fmaf(ww[j], (float)hv[j][3], a3);
        }
        e0 += 4; e1 += 4; e2 += 4; e3 += 4;
    }

    char* ub = (char*)u;
    half4 o;
    o[0] = (_Float16)(a0 * 0.5f);
    o[1] = (_Float16)(a1 * 0.5f);
    o[2] = (_Float16)(a2 * 0.5f);
    o[3] = (_Float16)(a3 * 0.5f);
    *(half4*)(ub + rowb + qoff) = o;   // wave writes 512B contiguous
}

// ---------------------------------------------------------------------------
// GEMM: out[N,64] = u[N,64] @ W[64,64] + b (unchanged)
// ---------------------------------------------------------------------------
template<bool HALF_OUT>
__global__ __launch_bounds__(256) void gemm64_kernel(
    const _Float16* __restrict__ u, const _Float16* __restrict__ Wt,
    const float* __restrict__ bias, void* __restrict__ outp)
{
    const int wid  = blockIdx.x * 4 + (threadIdx.x >> 6);
    const int lane = threadIdx.x & 63;
    const int m    = lane & 15;
    const int quad = lane >> 4;
    const size_t rowbase = (size_t)wid * 16;

    half8 bf[4][2];
#pragma unroll
    for (int c = 0; c < 4; ++c)
#pragma unroll
        for (int h = 0; h < 2; ++h)
            bf[c][h] = *(const half8*)(Wt + (size_t)(c * 16 + m) * DD + h * 32 + quad * 8);

    const half8 a0 = *(const half8*)(u + (rowbase + m) * DD +  0 + quad * 8);
    const half8 a1 = *(const half8*)(u + (rowbase + m) * DD + 32 + quad * 8);

    f32x4 acc[4];
#pragma unroll
    for (int c = 0; c < 4; ++c) {
        f32x4 z = {0.f, 0.f, 0.f, 0.f};
        z = __builtin_amdgcn_mfma_f32_16x16x32_f16(a0, bf[c][0], z, 0, 0, 0);
        z = __builtin_amdgcn_mfma_f32_16x16x32_f16(a1, bf[c][1], z, 0, 0, 0);
        acc[c] = z;
    }

#pragma unroll
    for (int c = 0; c < 4; ++c) {
        const float bv = bias[c * 16 + m];
#pragma unroll
        for (int r = 0; r < 4; ++r) {
            const size_t row = rowbase + quad * 4 + r;
            const float val = acc[c][r] + bv;
            if (HALF_OUT) ((_Float16*)outp)[row * DD + c * 16 + m] = (_Float16)val;
            else          ((float*)    outp)[row * DD + c * 16 + m] = val;
        }
    }
}

extern "C" void kernel_launch(void* const* d_in, const int* in_sizes, int n_in,
                              void* d_out, int out_size, void* d_ws, size_t ws_size,
                              hipStream_t stream) {
    const int*   edge_index  = (const int*)  d_in[0];
    const float* edge_weight = (const float*)d_in[1];
    const float* user_emb    = (const float*)d_in[2];
    const float* item_emb    = (const float*)d_in[3];
    const float* W1          = (const float*)d_in[4];
    const float* b1          = (const float*)d_in[5];
    const float* W2          = (const float*)d_in[6];
    const float* b2          = (const float*)d_in[7];
    float*       out         = (float*)d_out;

    // Workspace layout:
    char* ws = (char*)d_ws;
    _Float16* xh        = (_Float16*)(ws);               // 25,600,000 B (h1 aliases after layer 1)
    _Float16* u         = (_Float16*)(ws + 25600000);    // 25,600,000 B — also etmp during build
    int2*     etmp      = (int2*)    (ws + 25600000);    //   (alias of u)
    int2*     edges     = (int2*)    (ws + 51200000);    // 25,600,000 B (dst-sorted)
    int*      row_ptr   = (int*)     (ws + 76800000);    //    800,064 B
    int*      cseg      = (int*)     (ws + 78400064);    //    800,768 B (MSEG counters)
    int*      bofs      = (int*)     (ws + 79200832);    //    800,768 B (scanned MSEG)
    int*      bsum      = (int*)     (ws + 80001600);    //        512 B
    _Float16* Wt        = (_Float16*)(ws + 80002112);    //     16,384 B

    const int gemm_blocks = (NN / 16) / 4;               // 3125
    const int agg_blocks  = NN / 16;                     // 12500 (4 nodes/wave, 4 waves/block)

    // ---- bucket partition (segment-level scan) ----
    seg_hist_kernel     <<<GSEG,    256, 0, stream>>>(edge_index, cseg);
    scan_partials_kernel<<<NB_SCAN, 256, 0, stream>>>(cseg, bsum, MSEG);
    scan_top_kernel     <<<1,       128, 0, stream>>>(bsum, NB_SCAN);
    scan_write_kernel   <<<NB_SCAN, 256, 0, stream>>>(cseg, bsum, bofs, MSEG);

    // ---- append into buckets, then exact sort (also builds row_ptr) ----
    append_kernel      <<<GSEG, 256, 0, stream>>>(edge_index, edge_weight, bofs, etmp);
    bucket_sort_kernel <<<KB_,  256, 0, stream>>>(etmp, bofs, edges, row_ptr);

    // ---- fp16 conversions ----
    convert_x_kernel<<<(NN * DD / 4 + 255) / 256, 256, 0, stream>>>(user_emb, item_emb, xh);
    convert_w_kernel<<<(2 * DD * DD + 255) / 256, 256, 0, stream>>>(W1, W2, Wt);

    // ---- Layer 1 ----
    aggregate_kernel<<<agg_blocks, 256, 0, stream>>>(edges, row_ptr, xh, u);
    gemm64_kernel<true><<<gemm_blocks, 256, 0, stream>>>(u, Wt, b1, (void*)xh);

    // ---- Layer 2 ----
    aggregate_kernel<<<agg_blocks, 256, 0, stream>>>(edges, row_ptr, xh, u);
    gemm64_kernel<false><<<gemm_blocks, 256, 0, stream>>>(u, Wt + DD * DD, b2, (void*)out);
}